// Round 1
// baseline (422.277 us; speedup 1.0000x reference)
//
#include <hip/hip_runtime.h>

#define N_NODES   40000
#define N_EDGES   640000
#define D         128
#define N_CLASSES 40
#define N_GRAPHS  128

typedef unsigned int uint;

// ---------------- degree computation ----------------
__global__ void k_deg(const int* __restrict__ src, const int* __restrict__ dst,
                      uint* __restrict__ deg_out, uint* __restrict__ deg_in) {
    int t = blockIdx.x * blockDim.x + threadIdx.x;
    int stride = gridDim.x * blockDim.x;
    for (int e = t; e < N_EDGES; e += stride) {
        atomicAdd(&deg_out[src[e]], 1u);
        atomicAdd(&deg_in[dst[e]], 1u);
    }
}

// ---------------- exclusive scan of deg_in -> offsets (CSR row ptr) ----------------
__global__ __launch_bounds__(1024) void k_scan(const uint* __restrict__ deg_in,
                                               uint* __restrict__ offsets,
                                               uint* __restrict__ cursor) {
    __shared__ uint wsum[16];
    const int t = threadIdx.x;
    const int lane = t & 63;
    const int wave = t >> 6;
    const int CH = (N_NODES + 1023) / 1024;   // 40
    int beg = t * CH;
    int end = beg + CH; if (end > N_NODES) end = N_NODES;
    if (beg > N_NODES) beg = N_NODES;
    uint s = 0;
    for (int i = beg; i < end; ++i) s += deg_in[i];
    // inclusive wave scan
    uint v = s;
    for (int off = 1; off < 64; off <<= 1) {
        uint o = __shfl_up(v, off);
        if (lane >= off) v += o;
    }
    if (lane == 63) wsum[wave] = v;
    __syncthreads();
    if (t < 16) {
        uint w = wsum[t];
        for (int off = 1; off < 16; off <<= 1) {
            uint o = __shfl_up(w, off);
            if (t >= off) w += o;
        }
        wsum[t] = w;   // inclusive
    }
    __syncthreads();
    uint waveoff = (wave == 0) ? 0u : wsum[wave - 1];
    uint run = waveoff + v - s;   // exclusive base for this thread's chunk
    for (int i = beg; i < end; ++i) {
        offsets[i] = run;
        cursor[i]  = run;
        run += deg_in[i];
    }
    if (t == 1023) offsets[N_NODES] = run;
}

// ---------------- CSR fill ----------------
__global__ void k_fill(const int* __restrict__ src, const int* __restrict__ dst,
                       uint* __restrict__ cursor, int* __restrict__ csr_src) {
    int t = blockIdx.x * blockDim.x + threadIdx.x;
    int stride = gridDim.x * blockDim.x;
    for (int e = t; e < N_EDGES; e += stride) {
        uint pos = atomicAdd(&cursor[dst[e]], 1u);
        csr_src[pos] = src[e];
    }
}

// ---------------- graph boundary detection (graph_ids is sorted) ----------------
__global__ void k_bounds(const int* __restrict__ gid, int* __restrict__ bounds) {
    int i = blockIdx.x * blockDim.x + threadIdx.x;
    if (i >= N_NODES) return;
    int g = gid[i];
    if (i == 0) {
        for (int q = 0; q <= g; ++q) bounds[q] = 0;
    } else {
        int gp = gid[i - 1];
        for (int q = gp + 1; q <= g; ++q) bounds[q] = i;
    }
    if (i == N_NODES - 1) {
        for (int q = g + 1; q <= N_GRAPHS; ++q) bounds[q] = N_NODES;
    }
}

// ---------------- GEMM1: hW = (feat @ W1) * norm_src  ----------------
// two column-halves so LDS stays under 64KB: Ws 32KB + Fs ~8.4KB
#define GR 16
__global__ __launch_bounds__(256) void k_gemm1(const float* __restrict__ feat,
                                               const float* __restrict__ W1,
                                               const uint* __restrict__ deg_out,
                                               float* __restrict__ hW) {
    __shared__ float Ws[128 * 64];     // W1 columns [half*64, half*64+64)
    __shared__ float Fs[GR][132];      // padded rows (132: 16B-aligned, bank-spread)
    const int t = threadIdx.x;
    const int rloc = t >> 4;           // 0..15
    const int j4 = t & 15;             // 0..15 -> 4 cols each
    for (int half = 0; half < 2; ++half) {
        __syncthreads();
        for (int i = t; i < 128 * 16; i += 256) {  // 2048 float4 = 8192 floats
            int k = i >> 4, c4 = i & 15;
            *(float4*)&Ws[k * 64 + c4 * 4] =
                *(const float4*)&W1[k * 128 + half * 64 + c4 * 4];
        }
        __syncthreads();
        for (int rg = blockIdx.x; rg * GR < N_NODES; rg += gridDim.x) {
            int rowbase = rg * GR;
            __syncthreads();
            for (int i = t; i < GR * 32; i += 256) {  // 512 float4
                int r = i >> 5, c4 = i & 31;
                *(float4*)&Fs[r][c4 * 4] =
                    *(const float4*)&feat[(rowbase + r) * 128 + c4 * 4];
            }
            __syncthreads();
            float4 acc = {0.f, 0.f, 0.f, 0.f};
            for (int k = 0; k < 128; ++k) {
                float f = Fs[rloc][k];
                float4 w = *(const float4*)&Ws[k * 64 + j4 * 4];
                acc.x += f * w.x; acc.y += f * w.y;
                acc.z += f * w.z; acc.w += f * w.w;
            }
            int row = rowbase + rloc;
            float ns = rsqrtf(fmaxf((float)deg_out[row], 1.f));
            *(float4*)&hW[(size_t)row * 128 + half * 64 + j4 * 4] =
                make_float4(acc.x * ns, acc.y * ns, acc.z * ns, acc.w * ns);
        }
    }
}

// ---------------- pull SpMM: one wave per node, lane owns 2 features ----------------
// MODE 1: out = relu(acc*nd + b1) * ns      (fused conv1 epilogue, pre-scale for conv2)
// MODE 2: out = acc*nd                      (conv2 pre-pool rows)
template <int MODE>
__global__ __launch_bounds__(256) void k_spmm(const float* __restrict__ X,
                                              const int* __restrict__ csr_src,
                                              const uint* __restrict__ offsets,
                                              const uint* __restrict__ deg_out,
                                              const uint* __restrict__ deg_in,
                                              const float* __restrict__ b1,
                                              float* __restrict__ out) {
    const int lane = threadIdx.x & 63;
    int gw = (blockIdx.x * blockDim.x + threadIdx.x) >> 6;
    int nw = (gridDim.x * blockDim.x) >> 6;
    for (int i = gw; i < N_NODES; i += nw) {
        uint e = offsets[i], e1 = offsets[i + 1];
        float2 acc = {0.f, 0.f};
        for (; e + 4 <= e1; e += 4) {
            int s0 = csr_src[e], s1 = csr_src[e + 1];
            int s2 = csr_src[e + 2], s3 = csr_src[e + 3];
            float2 v0 = *(const float2*)&X[(size_t)s0 * D + lane * 2];
            float2 v1 = *(const float2*)&X[(size_t)s1 * D + lane * 2];
            float2 v2 = *(const float2*)&X[(size_t)s2 * D + lane * 2];
            float2 v3 = *(const float2*)&X[(size_t)s3 * D + lane * 2];
            acc.x += (v0.x + v1.x) + (v2.x + v3.x);
            acc.y += (v0.y + v1.y) + (v2.y + v3.y);
        }
        for (; e < e1; ++e) {
            int s = csr_src[e];
            float2 v = *(const float2*)&X[(size_t)s * D + lane * 2];
            acc.x += v.x; acc.y += v.y;
        }
        float nd = rsqrtf(fmaxf((float)deg_in[i], 1.f));
        float2 r;
        if (MODE == 1) {
            float ns = rsqrtf(fmaxf((float)deg_out[i], 1.f));
            float2 b = *(const float2*)&b1[lane * 2];
            r.x = fmaxf(acc.x * nd + b.x, 0.f) * ns;
            r.y = fmaxf(acc.y * nd + b.y, 0.f) * ns;
        } else {
            r.x = acc.x * nd;
            r.y = acc.y * nd;
        }
        *(float2*)&out[(size_t)i * D + lane * 2] = r;
    }
}

// ---------------- per-graph pool (contiguous segments) + W2 + classifier ----------------
__global__ __launch_bounds__(128) void k_final(const float* __restrict__ y,
                                               const int* __restrict__ bounds,
                                               const float* __restrict__ W2,
                                               const float* __restrict__ b2,
                                               const float* __restrict__ Wc,
                                               const float* __restrict__ bc,
                                               float* __restrict__ out) {
    __shared__ float P[D];
    __shared__ float hg[D];
    const int g = blockIdx.x;
    const int t = threadIdx.x;
    int r0 = bounds[g], r1 = bounds[g + 1];
    float acc = 0.f;
    for (int r = r0; r < r1; ++r) acc += y[(size_t)r * D + t];
    P[t] = acc;
    __syncthreads();
    float cntf = (float)(r1 - r0);
    float inv = 1.f / fmaxf(cntf, 1.f);
    float a2 = 0.f;
    for (int k = 0; k < D; ++k) a2 += P[k] * W2[k * D + t];
    hg[t] = a2 * inv + (cntf > 0.f ? b2[t] : 0.f);
    __syncthreads();
    if (t < N_CLASSES) {
        float o = bc[t];
        for (int k = 0; k < D; ++k) o += hg[k] * Wc[k * N_CLASSES + t];
        out[g * N_CLASSES + t] = o;
    }
}

extern "C" void kernel_launch(void* const* d_in, const int* in_sizes, int n_in,
                              void* d_out, int out_size, void* d_ws, size_t ws_size,
                              hipStream_t stream) {
    const float* feat = (const float*)d_in[0];
    const float* W1   = (const float*)d_in[1];
    const float* b1   = (const float*)d_in[2];
    const float* W2   = (const float*)d_in[3];
    const float* b2   = (const float*)d_in[4];
    const float* Wc   = (const float*)d_in[5];
    const float* bc   = (const float*)d_in[6];
    const int*   src  = (const int*)d_in[7];
    const int*   dst  = (const int*)d_in[8];
    const int*   gid  = (const int*)d_in[9];
    float* out = (float*)d_out;

    char* w = (char*)d_ws;
    uint* deg_out = (uint*)w; w += (size_t)N_NODES * 4;
    uint* deg_in  = (uint*)w; w += (size_t)N_NODES * 4;
    uint* offsets = (uint*)w; w += (size_t)(N_NODES + 4) * 4;
    uint* cursor  = (uint*)w; w += (size_t)N_NODES * 4;
    int*  csr     = (int*)w;  w += (size_t)N_EDGES * 4;
    int*  bounds  = (int*)w;  w += 132 * 4;
    float* hW  = (float*)w; w += (size_t)N_NODES * D * 4;
    float* h1s = (float*)w; w += (size_t)N_NODES * D * 4;
    float* y = hW;   // hW is dead after spmm<1>; reuse for conv2 output

    hipMemsetAsync(deg_out, 0, (size_t)N_NODES * 4, stream);
    hipMemsetAsync(deg_in, 0, (size_t)N_NODES * 4, stream);

    k_deg<<<1024, 256, 0, stream>>>(src, dst, deg_out, deg_in);
    k_scan<<<1, 1024, 0, stream>>>(deg_in, offsets, cursor);
    k_fill<<<1024, 256, 0, stream>>>(src, dst, cursor, csr);
    k_bounds<<<(N_NODES + 255) / 256, 256, 0, stream>>>(gid, bounds);
    k_gemm1<<<640, 256, 0, stream>>>(feat, W1, deg_out, hW);
    k_spmm<1><<<2048, 256, 0, stream>>>(hW, csr, offsets, deg_out, deg_in, b1, h1s);
    k_spmm<2><<<2048, 256, 0, stream>>>(h1s, csr, offsets, deg_out, deg_in, b1, y);
    k_final<<<N_GRAPHS, 128, 0, stream>>>(y, bounds, W2, b2, Wc, bc, out);
}

// Round 4
// 345.780 us; speedup vs baseline: 1.2212x; 1.2212x over previous
//
#include <hip/hip_runtime.h>

#define N_NODES   40000
#define N_EDGES   640000
#define D         128
#define N_CLASSES 40
#define N_GRAPHS  128

#define SCAN_CHUNK 2048
#define SCAN_NB    ((N_NODES + SCAN_CHUNK - 1) / SCAN_CHUNK)   // 20

typedef unsigned int uint;

// ---------------- degree computation ----------------
__global__ void k_deg(const int* __restrict__ src, const int* __restrict__ dst,
                      uint* __restrict__ deg_out, uint* __restrict__ deg_in) {
    int t = blockIdx.x * blockDim.x + threadIdx.x;
    int stride = gridDim.x * blockDim.x;
    for (int e = t; e < N_EDGES; e += stride) {
        atomicAdd(&deg_out[src[e]], 1u);
        atomicAdd(&deg_in[dst[e]], 1u);
    }
}

// ---------------- two-level scan: A = per-block sum ----------------
__global__ __launch_bounds__(256) void k_scan_a(const uint* __restrict__ deg_in,
                                                uint* __restrict__ blksum) {
    __shared__ uint wsum[4];
    const int b = blockIdx.x, t = threadIdx.x;
    const int lane = t & 63, wave = t >> 6;
    int base = b * SCAN_CHUNK + t * 8;
    uint s = 0;
    #pragma unroll
    for (int j = 0; j < 8; ++j) {
        int idx = base + j;
        s += (idx < N_NODES) ? deg_in[idx] : 0u;
    }
    #pragma unroll
    for (int off = 32; off > 0; off >>= 1) s += __shfl_down(s, off);
    if (lane == 0) wsum[wave] = s;
    __syncthreads();
    if (t == 0) blksum[b] = wsum[0] + wsum[1] + wsum[2] + wsum[3];
}

// ---------------- B = exclusive scan of block sums (1 wave) ----------------
__global__ void k_scan_b(const uint* __restrict__ blksum, uint* __restrict__ blkbase) {
    int t = threadIdx.x;   // 64 threads
    uint v = (t < SCAN_NB) ? blksum[t] : 0u;
    uint inc = v;
    #pragma unroll
    for (int off = 1; off < 64; off <<= 1) {
        uint o = __shfl_up(inc, off);
        if (t >= off) inc += o;
    }
    if (t < SCAN_NB) blkbase[t] = inc - v;
}

// ---------------- C = local scan + base, write offsets & cursor ----------------
__global__ __launch_bounds__(256) void k_scan_c(const uint* __restrict__ deg_in,
                                                const uint* __restrict__ blkbase,
                                                uint* __restrict__ offsets,
                                                uint* __restrict__ cursor) {
    __shared__ uint wsum[4];
    const int b = blockIdx.x, t = threadIdx.x;
    const int lane = t & 63, wave = t >> 6;
    int base = b * SCAN_CHUNK + t * 8;
    uint v[8];
    uint s = 0;
    #pragma unroll
    for (int j = 0; j < 8; ++j) {
        int idx = base + j;
        v[j] = (idx < N_NODES) ? deg_in[idx] : 0u;
        s += v[j];
    }
    uint inc = s;
    #pragma unroll
    for (int off = 1; off < 64; off <<= 1) {
        uint o = __shfl_up(inc, off);
        if (lane >= off) inc += o;
    }
    if (lane == 63) wsum[wave] = inc;
    __syncthreads();
    if (t < 4) {
        uint w = wsum[t];
        #pragma unroll
        for (int off = 1; off < 4; off <<= 1) {
            uint o = __shfl_up(w, off);
            if (t >= off) w += o;
        }
        wsum[t] = w;   // inclusive wave sums
    }
    __syncthreads();
    uint excl = inc - s + (wave ? wsum[wave - 1] : 0u) + blkbase[b];
    #pragma unroll
    for (int j = 0; j < 8; ++j) {
        int idx = base + j;
        if (idx < N_NODES) { offsets[idx] = excl; cursor[idx] = excl; }
        excl += v[j];
    }
    if (b == SCAN_NB - 1 && t == 255) offsets[N_NODES] = excl;
}

// ---------------- CSR fill ----------------
__global__ void k_fill(const int* __restrict__ src, const int* __restrict__ dst,
                       uint* __restrict__ cursor, int* __restrict__ csr_src) {
    int t = blockIdx.x * blockDim.x + threadIdx.x;
    int stride = gridDim.x * blockDim.x;
    for (int e = t; e < N_EDGES; e += stride) {
        uint pos = atomicAdd(&cursor[dst[e]], 1u);
        csr_src[pos] = src[e];
    }
}

// ---------------- graph boundary detection (graph_ids is sorted) ----------------
__global__ void k_bounds(const int* __restrict__ gid, int* __restrict__ bounds) {
    int i = blockIdx.x * blockDim.x + threadIdx.x;
    if (i >= N_NODES) return;
    int g = gid[i];
    if (i == 0) {
        for (int q = 0; q <= g; ++q) bounds[q] = 0;
    } else {
        int gp = gid[i - 1];
        for (int q = gp + 1; q <= g; ++q) bounds[q] = i;
    }
    if (i == N_NODES - 1) {
        for (int q = g + 1; q <= N_GRAPHS; ++q) bounds[q] = N_NODES;
    }
}

// ---------------- GEMM1: hW = (feat @ W1) * norm_src  ----------------
#define GR 16
__global__ __launch_bounds__(256) void k_gemm1(const float* __restrict__ feat,
                                               const float* __restrict__ W1,
                                               const uint* __restrict__ deg_out,
                                               float* __restrict__ hW) {
    __shared__ float Ws[128 * 64];
    __shared__ float Fs[GR][132];
    const int t = threadIdx.x;
    const int rloc = t >> 4;
    const int j4 = t & 15;
    for (int half = 0; half < 2; ++half) {
        __syncthreads();
        for (int i = t; i < 128 * 16; i += 256) {
            int k = i >> 4, c4 = i & 15;
            *(float4*)&Ws[k * 64 + c4 * 4] =
                *(const float4*)&W1[k * 128 + half * 64 + c4 * 4];
        }
        __syncthreads();
        for (int rg = blockIdx.x; rg * GR < N_NODES; rg += gridDim.x) {
            int rowbase = rg * GR;
            __syncthreads();
            for (int i = t; i < GR * 32; i += 256) {
                int r = i >> 5, c4 = i & 31;
                *(float4*)&Fs[r][c4 * 4] =
                    *(const float4*)&feat[(rowbase + r) * 128 + c4 * 4];
            }
            __syncthreads();
            float4 acc = {0.f, 0.f, 0.f, 0.f};
            for (int k = 0; k < 128; ++k) {
                float f = Fs[rloc][k];
                float4 w = *(const float4*)&Ws[k * 64 + j4 * 4];
                acc.x += f * w.x; acc.y += f * w.y;
                acc.z += f * w.z; acc.w += f * w.w;
            }
            int row = rowbase + rloc;
            float ns = rsqrtf(fmaxf((float)deg_out[row], 1.f));
            *(float4*)&hW[(size_t)row * 128 + half * 64 + j4 * 4] =
                make_float4(acc.x * ns, acc.y * ns, acc.z * ns, acc.w * ns);
        }
    }
}

// ---------------- pull SpMM: one wave per node, lane owns 2 features ----------------
template <int MODE>
__global__ __launch_bounds__(256) void k_spmm(const float* __restrict__ X,
                                              const int* __restrict__ csr_src,
                                              const uint* __restrict__ offsets,
                                              const uint* __restrict__ deg_out,
                                              const uint* __restrict__ deg_in,
                                              const float* __restrict__ b1,
                                              float* __restrict__ out) {
    const int lane = threadIdx.x & 63;
    int gw = (blockIdx.x * blockDim.x + threadIdx.x) >> 6;
    int nw = (gridDim.x * blockDim.x) >> 6;
    for (int i = gw; i < N_NODES; i += nw) {
        uint e = offsets[i], e1 = offsets[i + 1];
        float2 acc = {0.f, 0.f};
        for (; e + 4 <= e1; e += 4) {
            int s0 = csr_src[e], s1 = csr_src[e + 1];
            int s2 = csr_src[e + 2], s3 = csr_src[e + 3];
            float2 v0 = *(const float2*)&X[(size_t)s0 * D + lane * 2];
            float2 v1 = *(const float2*)&X[(size_t)s1 * D + lane * 2];
            float2 v2 = *(const float2*)&X[(size_t)s2 * D + lane * 2];
            float2 v3 = *(const float2*)&X[(size_t)s3 * D + lane * 2];
            acc.x += (v0.x + v1.x) + (v2.x + v3.x);
            acc.y += (v0.y + v1.y) + (v2.y + v3.y);
        }
        for (; e < e1; ++e) {
            int s = csr_src[e];
            float2 v = *(const float2*)&X[(size_t)s * D + lane * 2];
            acc.x += v.x; acc.y += v.y;
        }
        float nd = rsqrtf(fmaxf((float)deg_in[i], 1.f));
        float2 r;
        if (MODE == 1) {
            float ns = rsqrtf(fmaxf((float)deg_out[i], 1.f));
            float2 b = *(const float2*)&b1[lane * 2];
            r.x = fmaxf(acc.x * nd + b.x, 0.f) * ns;
            r.y = fmaxf(acc.y * nd + b.y, 0.f) * ns;
        } else {
            r.x = acc.x * nd;
            r.y = acc.y * nd;
        }
        *(float2*)&out[(size_t)i * D + lane * 2] = r;
    }
}

// ---------------- per-graph pool + W2 + classifier ----------------
__global__ __launch_bounds__(128) void k_final(const float* __restrict__ y,
                                               const int* __restrict__ bounds,
                                               const float* __restrict__ W2,
                                               const float* __restrict__ b2,
                                               const float* __restrict__ Wc,
                                               const float* __restrict__ bc,
                                               float* __restrict__ out) {
    __shared__ float P[D];
    __shared__ float hg[D];
    const int g = blockIdx.x;
    const int t = threadIdx.x;
    int r0 = bounds[g], r1 = bounds[g + 1];
    float acc = 0.f;
    for (int r = r0; r < r1; ++r) acc += y[(size_t)r * D + t];
    P[t] = acc;
    __syncthreads();
    float cntf = (float)(r1 - r0);
    float inv = 1.f / fmaxf(cntf, 1.f);
    float a2 = 0.f;
    for (int k = 0; k < D; ++k) a2 += P[k] * W2[k * D + t];
    hg[t] = a2 * inv + (cntf > 0.f ? b2[t] : 0.f);
    __syncthreads();
    if (t < N_CLASSES) {
        float o = bc[t];
        for (int k = 0; k < D; ++k) o += hg[k] * Wc[k * N_CLASSES + t];
        out[g * N_CLASSES + t] = o;
    }
}

extern "C" void kernel_launch(void* const* d_in, const int* in_sizes, int n_in,
                              void* d_out, int out_size, void* d_ws, size_t ws_size,
                              hipStream_t stream) {
    const float* feat = (const float*)d_in[0];
    const float* W1   = (const float*)d_in[1];
    const float* b1   = (const float*)d_in[2];
    const float* W2   = (const float*)d_in[3];
    const float* b2   = (const float*)d_in[4];
    const float* Wc   = (const float*)d_in[5];
    const float* bc   = (const float*)d_in[6];
    const int*   src  = (const int*)d_in[7];
    const int*   dst  = (const int*)d_in[8];
    const int*   gid  = (const int*)d_in[9];
    float* out = (float*)d_out;

    char* w = (char*)d_ws;
    uint* deg_out = (uint*)w; w += (size_t)N_NODES * 4;
    uint* deg_in  = (uint*)w; w += (size_t)N_NODES * 4;
    uint* offsets = (uint*)w; w += (size_t)(N_NODES + 4) * 4;
    uint* cursor  = (uint*)w; w += (size_t)N_NODES * 4;
    int*  csr     = (int*)w;  w += (size_t)N_EDGES * 4;
    int*  bounds  = (int*)w;  w += 132 * 4;
    uint* blksum  = (uint*)w; w += 32 * 4;
    uint* blkbase = (uint*)w; w += 32 * 4;
    float* hW  = (float*)w; w += (size_t)N_NODES * D * 4;
    float* h1s = (float*)w; w += (size_t)N_NODES * D * 4;
    float* y = hW;   // hW dead after spmm<1>; reuse for conv2 output

    hipMemsetAsync(deg_out, 0, (size_t)N_NODES * 4, stream);
    hipMemsetAsync(deg_in, 0, (size_t)N_NODES * 4, stream);

    k_deg<<<1024, 256, 0, stream>>>(src, dst, deg_out, deg_in);
    k_scan_a<<<SCAN_NB, 256, 0, stream>>>(deg_in, blksum);
    k_scan_b<<<1, 64, 0, stream>>>(blksum, blkbase);
    k_scan_c<<<SCAN_NB, 256, 0, stream>>>(deg_in, blkbase, offsets, cursor);
    k_fill<<<1024, 256, 0, stream>>>(src, dst, cursor, csr);
    k_bounds<<<(N_NODES + 255) / 256, 256, 0, stream>>>(gid, bounds);
    k_gemm1<<<640, 256, 0, stream>>>(feat, W1, deg_out, hW);
    k_spmm<1><<<2048, 256, 0, stream>>>(hW, csr, offsets, deg_out, deg_in, b1, h1s);
    k_spmm<2><<<2048, 256, 0, stream>>>(h1s, csr, offsets, deg_out, deg_in, b1, y);
    k_final<<<N_GRAPHS, 128, 0, stream>>>(y, bounds, W2, b2, Wc, bc, out);
}

// Round 5
// 291.963 us; speedup vs baseline: 1.4463x; 1.1843x over previous
//
#include <hip/hip_runtime.h>

#define N_NODES   40000
#define N_EDGES   640000
#define D         128
#define N_CLASSES 40
#define N_GRAPHS  128

#define SCAN_CHUNK 2048
#define SCAN_NB    ((N_NODES + SCAN_CHUNK - 1) / SCAN_CHUNK)   // 20
#define PCH 64
#define POOL_NB (N_NODES / PCH)                                 // 625

typedef unsigned int uint;

// ---------------- degree computation ----------------
__global__ void k_deg(const int* __restrict__ src, const int* __restrict__ dst,
                      uint* __restrict__ deg_out, uint* __restrict__ deg_in) {
    int t = blockIdx.x * blockDim.x + threadIdx.x;
    int stride = gridDim.x * blockDim.x;
    for (int e = t; e < N_EDGES; e += stride) {
        atomicAdd(&deg_out[src[e]], 1u);
        atomicAdd(&deg_in[dst[e]], 1u);
    }
}

// ---------------- two-level scan: A = per-block sum ----------------
__global__ __launch_bounds__(256) void k_scan_a(const uint* __restrict__ deg_in,
                                                uint* __restrict__ blksum) {
    __shared__ uint wsum[4];
    const int b = blockIdx.x, t = threadIdx.x;
    const int lane = t & 63, wave = t >> 6;
    int base = b * SCAN_CHUNK + t * 8;
    uint s = 0;
    #pragma unroll
    for (int j = 0; j < 8; ++j) {
        int idx = base + j;
        s += (idx < N_NODES) ? deg_in[idx] : 0u;
    }
    #pragma unroll
    for (int off = 32; off > 0; off >>= 1) s += __shfl_down(s, off);
    if (lane == 0) wsum[wave] = s;
    __syncthreads();
    if (t == 0) blksum[b] = wsum[0] + wsum[1] + wsum[2] + wsum[3];
}

// ---------------- B = exclusive scan of block sums (1 wave) ----------------
__global__ void k_scan_b(const uint* __restrict__ blksum, uint* __restrict__ blkbase) {
    int t = threadIdx.x;   // 64 threads
    uint v = (t < SCAN_NB) ? blksum[t] : 0u;
    uint inc = v;
    #pragma unroll
    for (int off = 1; off < 64; off <<= 1) {
        uint o = __shfl_up(inc, off);
        if (t >= off) inc += o;
    }
    if (t < SCAN_NB) blkbase[t] = inc - v;
}

// ---------------- C = local scan + base, write offsets & cursor ----------------
__global__ __launch_bounds__(256) void k_scan_c(const uint* __restrict__ deg_in,
                                                const uint* __restrict__ blkbase,
                                                uint* __restrict__ offsets,
                                                uint* __restrict__ cursor) {
    __shared__ uint wsum[4];
    const int b = blockIdx.x, t = threadIdx.x;
    const int lane = t & 63, wave = t >> 6;
    int base = b * SCAN_CHUNK + t * 8;
    uint v[8];
    uint s = 0;
    #pragma unroll
    for (int j = 0; j < 8; ++j) {
        int idx = base + j;
        v[j] = (idx < N_NODES) ? deg_in[idx] : 0u;
        s += v[j];
    }
    uint inc = s;
    #pragma unroll
    for (int off = 1; off < 64; off <<= 1) {
        uint o = __shfl_up(inc, off);
        if (lane >= off) inc += o;
    }
    if (lane == 63) wsum[wave] = inc;
    __syncthreads();
    if (t < 4) {
        uint w = wsum[t];
        #pragma unroll
        for (int off = 1; off < 4; off <<= 1) {
            uint o = __shfl_up(w, off);
            if (t >= off) w += o;
        }
        wsum[t] = w;   // inclusive wave sums
    }
    __syncthreads();
    uint excl = inc - s + (wave ? wsum[wave - 1] : 0u) + blkbase[b];
    #pragma unroll
    for (int j = 0; j < 8; ++j) {
        int idx = base + j;
        if (idx < N_NODES) { offsets[idx] = excl; cursor[idx] = excl; }
        excl += v[j];
    }
    if (b == SCAN_NB - 1 && t == 255) offsets[N_NODES] = excl;
}

// ---------------- CSR fill ----------------
__global__ void k_fill(const int* __restrict__ src, const int* __restrict__ dst,
                       uint* __restrict__ cursor, int* __restrict__ csr_src) {
    int t = blockIdx.x * blockDim.x + threadIdx.x;
    int stride = gridDim.x * blockDim.x;
    for (int e = t; e < N_EDGES; e += stride) {
        uint pos = atomicAdd(&cursor[dst[e]], 1u);
        csr_src[pos] = src[e];
    }
}

// ---------------- graph boundary detection (graph_ids is sorted) ----------------
__global__ void k_bounds(const int* __restrict__ gid, int* __restrict__ bounds) {
    int i = blockIdx.x * blockDim.x + threadIdx.x;
    if (i >= N_NODES) return;
    int g = gid[i];
    if (i == 0) {
        for (int q = 0; q <= g; ++q) bounds[q] = 0;
    } else {
        int gp = gid[i - 1];
        for (int q = gp + 1; q <= g; ++q) bounds[q] = i;
    }
    if (i == N_NODES - 1) {
        for (int q = g + 1; q <= N_GRAPHS; ++q) bounds[q] = N_NODES;
    }
}

// ---------------- fused classifier weight: Wfused = W2 @ Wc, bfused = b2 @ Wc ----
__global__ void k_fuse(const float* __restrict__ W2, const float* __restrict__ b2,
                       const float* __restrict__ Wc,
                       float* __restrict__ Wfused, float* __restrict__ bfused) {
    int k = blockIdx.x;        // 0..128 (128 = b2 row)
    int c = threadIdx.x;       // 64 threads, 40 active
    if (c >= N_CLASSES) return;
    const float* row = (k < D) ? &W2[k * D] : b2;
    float s = 0.f;
    for (int j = 0; j < D; ++j) s += row[j] * Wc[j * N_CLASSES + c];
    if (k < D) Wfused[k * N_CLASSES + c] = s;
    else bfused[c] = s;
}

// ---------------- GEMM1: hW = (feat @ W1) * norm_src  ----------------
#define GR 16
__global__ __launch_bounds__(256) void k_gemm1(const float* __restrict__ feat,
                                               const float* __restrict__ W1,
                                               const uint* __restrict__ deg_out,
                                               float* __restrict__ hW) {
    __shared__ float Ws[128 * 64];
    __shared__ float Fs[GR][132];
    const int t = threadIdx.x;
    const int rloc = t >> 4;
    const int j4 = t & 15;
    for (int half = 0; half < 2; ++half) {
        __syncthreads();
        for (int i = t; i < 128 * 16; i += 256) {
            int k = i >> 4, c4 = i & 15;
            *(float4*)&Ws[k * 64 + c4 * 4] =
                *(const float4*)&W1[k * 128 + half * 64 + c4 * 4];
        }
        __syncthreads();
        for (int rg = blockIdx.x; rg * GR < N_NODES; rg += gridDim.x) {
            int rowbase = rg * GR;
            __syncthreads();
            for (int i = t; i < GR * 32; i += 256) {
                int r = i >> 5, c4 = i & 31;
                *(float4*)&Fs[r][c4 * 4] =
                    *(const float4*)&feat[(rowbase + r) * 128 + c4 * 4];
            }
            __syncthreads();
            float4 acc = {0.f, 0.f, 0.f, 0.f};
            for (int k = 0; k < 128; ++k) {
                float f = Fs[rloc][k];
                float4 w = *(const float4*)&Ws[k * 64 + j4 * 4];
                acc.x += f * w.x; acc.y += f * w.y;
                acc.z += f * w.z; acc.w += f * w.w;
            }
            int row = rowbase + rloc;
            float ns = rsqrtf(fmaxf((float)deg_out[row], 1.f));
            *(float4*)&hW[(size_t)row * 128 + half * 64 + j4 * 4] =
                make_float4(acc.x * ns, acc.y * ns, acc.z * ns, acc.w * ns);
        }
    }
}

// ---------------- pull SpMM: one wave per node, lane owns 2 features ----------------
template <int MODE>
__global__ __launch_bounds__(256) void k_spmm(const float* __restrict__ X,
                                              const int* __restrict__ csr_src,
                                              const uint* __restrict__ offsets,
                                              const uint* __restrict__ deg_out,
                                              const uint* __restrict__ deg_in,
                                              const float* __restrict__ b1,
                                              float* __restrict__ out) {
    const int lane = threadIdx.x & 63;
    int gw = (blockIdx.x * blockDim.x + threadIdx.x) >> 6;
    int nw = (gridDim.x * blockDim.x) >> 6;
    for (int i = gw; i < N_NODES; i += nw) {
        uint e = offsets[i], e1 = offsets[i + 1];
        float2 acc = {0.f, 0.f};
        for (; e + 4 <= e1; e += 4) {
            int s0 = csr_src[e], s1 = csr_src[e + 1];
            int s2 = csr_src[e + 2], s3 = csr_src[e + 3];
            float2 v0 = *(const float2*)&X[(size_t)s0 * D + lane * 2];
            float2 v1 = *(const float2*)&X[(size_t)s1 * D + lane * 2];
            float2 v2 = *(const float2*)&X[(size_t)s2 * D + lane * 2];
            float2 v3 = *(const float2*)&X[(size_t)s3 * D + lane * 2];
            acc.x += (v0.x + v1.x) + (v2.x + v3.x);
            acc.y += (v0.y + v1.y) + (v2.y + v3.y);
        }
        for (; e < e1; ++e) {
            int s = csr_src[e];
            float2 v = *(const float2*)&X[(size_t)s * D + lane * 2];
            acc.x += v.x; acc.y += v.y;
        }
        float nd = rsqrtf(fmaxf((float)deg_in[i], 1.f));
        float2 r;
        if (MODE == 1) {
            float ns = rsqrtf(fmaxf((float)deg_out[i], 1.f));
            float2 b = *(const float2*)&b1[lane * 2];
            r.x = fmaxf(acc.x * nd + b.x, 0.f) * ns;
            r.y = fmaxf(acc.y * nd + b.y, 0.f) * ns;
        } else {
            r.x = acc.x * nd;
            r.y = acc.y * nd;
        }
        *(float2*)&out[(size_t)i * D + lane * 2] = r;
    }
}

// ---------------- parallel segmented pool: sums[g][t] += y rows ----------------
__global__ __launch_bounds__(128) void k_pool(const float* __restrict__ y,
                                              const int* __restrict__ gid,
                                              float* __restrict__ sums) {
    __shared__ int sg[PCH];
    const int b = blockIdx.x, t = threadIdx.x;
    const int base = b * PCH;
    if (t < PCH) sg[t] = gid[base + t];
    __syncthreads();
    float acc = 0.f;
    int cur = sg[0];
    for (int j = 0; j < PCH; ++j) {
        int g = sg[j];                       // uniform across block -> no divergence
        if (g != cur) {
            atomicAdd(&sums[cur * D + t], acc);
            acc = 0.f; cur = g;
        }
        acc += y[(size_t)(base + j) * D + t];
    }
    atomicAdd(&sums[cur * D + t], acc);
}

// ---------------- per-graph classifier matvec ----------------
__global__ __launch_bounds__(64) void k_out(const float* __restrict__ sums,
                                            const int* __restrict__ bounds,
                                            const float* __restrict__ Wfused,
                                            const float* __restrict__ bfused,
                                            const float* __restrict__ bc,
                                            float* __restrict__ out) {
    int g = blockIdx.x, c = threadIdx.x;
    if (c >= N_CLASSES) return;
    int cnt = bounds[g + 1] - bounds[g];
    float inv = (cnt > 0) ? 1.f / (float)cnt : 0.f;
    float s = 0.f;
    #pragma unroll 8
    for (int k = 0; k < D; ++k) s += sums[g * D + k] * Wfused[k * N_CLASSES + c];
    out[g * N_CLASSES + c] = s * inv + (cnt > 0 ? bfused[c] : 0.f) + bc[c];
}

extern "C" void kernel_launch(void* const* d_in, const int* in_sizes, int n_in,
                              void* d_out, int out_size, void* d_ws, size_t ws_size,
                              hipStream_t stream) {
    const float* feat = (const float*)d_in[0];
    const float* W1   = (const float*)d_in[1];
    const float* b1   = (const float*)d_in[2];
    const float* W2   = (const float*)d_in[3];
    const float* b2   = (const float*)d_in[4];
    const float* Wc   = (const float*)d_in[5];
    const float* bc   = (const float*)d_in[6];
    const int*   src  = (const int*)d_in[7];
    const int*   dst  = (const int*)d_in[8];
    const int*   gid  = (const int*)d_in[9];
    float* out = (float*)d_out;

    char* w = (char*)d_ws;
    uint* deg_out = (uint*)w; w += (size_t)N_NODES * 4;
    uint* deg_in  = (uint*)w; w += (size_t)N_NODES * 4;
    uint* offsets = (uint*)w; w += (size_t)(N_NODES + 4) * 4;
    uint* cursor  = (uint*)w; w += (size_t)N_NODES * 4;
    int*  csr     = (int*)w;  w += (size_t)N_EDGES * 4;
    int*  bounds  = (int*)w;  w += 132 * 4;
    uint* blksum  = (uint*)w; w += 32 * 4;
    uint* blkbase = (uint*)w; w += 32 * 4;
    float* Wfused = (float*)w; w += (size_t)D * N_CLASSES * 4;
    float* bfused = (float*)w; w += 64 * 4;
    float* sums   = (float*)w; w += (size_t)N_GRAPHS * D * 4;
    float* hW  = (float*)w; w += (size_t)N_NODES * D * 4;
    float* h1s = (float*)w; w += (size_t)N_NODES * D * 4;
    float* y = hW;   // hW dead after spmm<1>; reuse for conv2 output

    hipMemsetAsync(deg_out, 0, (size_t)N_NODES * 4, stream);
    hipMemsetAsync(deg_in, 0, (size_t)N_NODES * 4, stream);
    hipMemsetAsync(sums, 0, (size_t)N_GRAPHS * D * 4, stream);

    k_fuse<<<D + 1, 64, 0, stream>>>(W2, b2, Wc, Wfused, bfused);
    k_deg<<<1024, 256, 0, stream>>>(src, dst, deg_out, deg_in);
    k_scan_a<<<SCAN_NB, 256, 0, stream>>>(deg_in, blksum);
    k_scan_b<<<1, 64, 0, stream>>>(blksum, blkbase);
    k_scan_c<<<SCAN_NB, 256, 0, stream>>>(deg_in, blkbase, offsets, cursor);
    k_fill<<<1024, 256, 0, stream>>>(src, dst, cursor, csr);
    k_bounds<<<(N_NODES + 255) / 256, 256, 0, stream>>>(gid, bounds);
    k_gemm1<<<640, 256, 0, stream>>>(feat, W1, deg_out, hW);
    k_spmm<1><<<2048, 256, 0, stream>>>(hW, csr, offsets, deg_out, deg_in, b1, h1s);
    k_spmm<2><<<2048, 256, 0, stream>>>(h1s, csr, offsets, deg_out, deg_in, b1, y);
    k_pool<<<POOL_NB, 128, 0, stream>>>(y, gid, sums);
    k_out<<<N_GRAPHS, 64, 0, stream>>>(sums, bounds, Wfused, bfused, bc, out);
}

// Round 6
// 250.595 us; speedup vs baseline: 1.6851x; 1.1651x over previous
//
#include <hip/hip_runtime.h>
#include <hip/hip_fp16.h>

#define N_NODES   40000
#define N_EDGES   640000
#define D         128
#define N_CLASSES 40
#define N_GRAPHS  128

#define SCAN_CHUNK 2048
#define SCAN_NB    ((N_NODES + SCAN_CHUNK - 1) / SCAN_CHUNK)   // 20
#define PCH 64
#define POOL_NB (N_NODES / PCH)                                 // 625

typedef unsigned int uint;

// ---------------- degree computation ----------------
__global__ void k_deg(const int* __restrict__ src, const int* __restrict__ dst,
                      uint* __restrict__ deg_out, uint* __restrict__ deg_in) {
    int t = blockIdx.x * blockDim.x + threadIdx.x;
    int stride = gridDim.x * blockDim.x;
    for (int e = t; e < N_EDGES; e += stride) {
        atomicAdd(&deg_out[src[e]], 1u);
        atomicAdd(&deg_in[dst[e]], 1u);
    }
}

// ---------------- two-level scan: A = per-block sum ----------------
__global__ __launch_bounds__(256) void k_scan_a(const uint* __restrict__ deg_in,
                                                uint* __restrict__ blksum) {
    __shared__ uint wsum[4];
    const int b = blockIdx.x, t = threadIdx.x;
    const int lane = t & 63, wave = t >> 6;
    int base = b * SCAN_CHUNK + t * 8;
    uint s = 0;
    #pragma unroll
    for (int j = 0; j < 8; ++j) {
        int idx = base + j;
        s += (idx < N_NODES) ? deg_in[idx] : 0u;
    }
    #pragma unroll
    for (int off = 32; off > 0; off >>= 1) s += __shfl_down(s, off);
    if (lane == 0) wsum[wave] = s;
    __syncthreads();
    if (t == 0) blksum[b] = wsum[0] + wsum[1] + wsum[2] + wsum[3];
}

// ---------------- B = exclusive scan of block sums (1 wave) ----------------
__global__ void k_scan_b(const uint* __restrict__ blksum, uint* __restrict__ blkbase) {
    int t = threadIdx.x;   // 64 threads
    uint v = (t < SCAN_NB) ? blksum[t] : 0u;
    uint inc = v;
    #pragma unroll
    for (int off = 1; off < 64; off <<= 1) {
        uint o = __shfl_up(inc, off);
        if (t >= off) inc += o;
    }
    if (t < SCAN_NB) blkbase[t] = inc - v;
}

// ------ C = local scan + base, write offsets & cursor; also graph bounds ------
__global__ __launch_bounds__(256) void k_scan_c(const uint* __restrict__ deg_in,
                                                const uint* __restrict__ blkbase,
                                                uint* __restrict__ offsets,
                                                uint* __restrict__ cursor,
                                                const int* __restrict__ gid,
                                                int* __restrict__ bounds) {
    __shared__ uint wsum[4];
    const int b = blockIdx.x, t = threadIdx.x;
    const int lane = t & 63, wave = t >> 6;
    int base = b * SCAN_CHUNK + t * 8;
    uint v[8];
    uint s = 0;
    #pragma unroll
    for (int j = 0; j < 8; ++j) {
        int idx = base + j;
        v[j] = (idx < N_NODES) ? deg_in[idx] : 0u;
        s += v[j];
    }
    uint inc = s;
    #pragma unroll
    for (int off = 1; off < 64; off <<= 1) {
        uint o = __shfl_up(inc, off);
        if (lane >= off) inc += o;
    }
    if (lane == 63) wsum[wave] = inc;
    __syncthreads();
    if (t < 4) {
        uint w = wsum[t];
        #pragma unroll
        for (int off = 1; off < 4; off <<= 1) {
            uint o = __shfl_up(w, off);
            if (t >= off) w += o;
        }
        wsum[t] = w;   // inclusive wave sums
    }
    __syncthreads();
    uint excl = inc - s + (wave ? wsum[wave - 1] : 0u) + blkbase[b];
    #pragma unroll
    for (int j = 0; j < 8; ++j) {
        int idx = base + j;
        if (idx < N_NODES) { offsets[idx] = excl; cursor[idx] = excl; }
        excl += v[j];
    }
    if (b == SCAN_NB - 1 && t == 255) offsets[N_NODES] = excl;
    // ---- graph bounds (gid sorted) ----
    for (int j = 0; j < 8; ++j) {
        int idx = base + j;
        if (idx >= N_NODES) break;
        int g = gid[idx];
        if (idx == 0) {
            for (int q = 0; q <= g; ++q) bounds[q] = 0;
        } else {
            int gp = gid[idx - 1];
            for (int q = gp + 1; q <= g; ++q) bounds[q] = idx;
        }
        if (idx == N_NODES - 1) {
            for (int q = g + 1; q <= N_GRAPHS; ++q) bounds[q] = N_NODES;
        }
    }
}

// ---------------- CSR fill ----------------
__global__ void k_fill(const int* __restrict__ src, const int* __restrict__ dst,
                       uint* __restrict__ cursor, int* __restrict__ csr_src) {
    int t = blockIdx.x * blockDim.x + threadIdx.x;
    int stride = gridDim.x * blockDim.x;
    for (int e = t; e < N_EDGES; e += stride) {
        uint pos = atomicAdd(&cursor[dst[e]], 1u);
        csr_src[pos] = src[e];
    }
}

// ---------------- fused classifier weight: Wfused = W2 @ Wc, bfused = b2 @ Wc ----
__global__ void k_fuse(const float* __restrict__ W2, const float* __restrict__ b2,
                       const float* __restrict__ Wc,
                       float* __restrict__ Wfused, float* __restrict__ bfused) {
    int k = blockIdx.x;        // 0..128 (128 = b2 row)
    int c = threadIdx.x;       // 64 threads, 40 active
    if (c >= N_CLASSES) return;
    const float* row = (k < D) ? &W2[k * D] : b2;
    float s = 0.f;
    for (int j = 0; j < D; ++j) s += row[j] * Wc[j * N_CLASSES + c];
    if (k < D) Wfused[k * N_CLASSES + c] = s;
    else bfused[c] = s;
}

// ---------------- GEMM1: hW = fp16( (feat @ W1) * norm_src )  ----------------
#define GR 16
__global__ __launch_bounds__(256) void k_gemm1(const float* __restrict__ feat,
                                               const float* __restrict__ W1,
                                               const uint* __restrict__ deg_out,
                                               __half* __restrict__ hW) {
    __shared__ float Ws[128 * 64];
    __shared__ float Fs[GR][132];
    const int t = threadIdx.x;
    const int rloc = t >> 4;
    const int j4 = t & 15;
    for (int half = 0; half < 2; ++half) {
        __syncthreads();
        for (int i = t; i < 128 * 16; i += 256) {
            int k = i >> 4, c4 = i & 15;
            *(float4*)&Ws[k * 64 + c4 * 4] =
                *(const float4*)&W1[k * 128 + half * 64 + c4 * 4];
        }
        __syncthreads();
        for (int rg = blockIdx.x; rg * GR < N_NODES; rg += gridDim.x) {
            int rowbase = rg * GR;
            __syncthreads();
            for (int i = t; i < GR * 32; i += 256) {
                int r = i >> 5, c4 = i & 31;
                *(float4*)&Fs[r][c4 * 4] =
                    *(const float4*)&feat[(rowbase + r) * 128 + c4 * 4];
            }
            __syncthreads();
            float4 acc = {0.f, 0.f, 0.f, 0.f};
            for (int k = 0; k < 128; ++k) {
                float f = Fs[rloc][k];
                float4 w = *(const float4*)&Ws[k * 64 + j4 * 4];
                acc.x += f * w.x; acc.y += f * w.y;
                acc.z += f * w.z; acc.w += f * w.w;
            }
            int row = rowbase + rloc;
            float ns = rsqrtf(fmaxf((float)deg_out[row], 1.f));
            __half2 p0 = __floats2half2_rn(acc.x * ns, acc.y * ns);
            __half2 p1 = __floats2half2_rn(acc.z * ns, acc.w * ns);
            uint2 pk;
            pk.x = *(uint*)&p0;
            pk.y = *(uint*)&p1;
            *(uint2*)&hW[(size_t)row * 128 + half * 64 + j4 * 4] = pk;
        }
    }
}

// ------- pull SpMM (fp16 gather, fp32 accum): one wave per node, lane = 2 feats ----
// MODE 1: out(half) = relu(acc*nd + b1) * ns      (conv1 epilogue, pre-scaled)
// MODE 2: out(float)= acc*nd                      (conv2 pre-pool rows)
template <int MODE>
__global__ __launch_bounds__(256) void k_spmm(const __half* __restrict__ X,
                                              const int* __restrict__ csr_src,
                                              const uint* __restrict__ offsets,
                                              const uint* __restrict__ deg_out,
                                              const uint* __restrict__ deg_in,
                                              const float* __restrict__ b1,
                                              void* __restrict__ outp) {
    const int lane = threadIdx.x & 63;
    const __half2* __restrict__ Xr = (const __half2*)X;   // row = 64 half2
    int gw = (blockIdx.x * blockDim.x + threadIdx.x) >> 6;
    int nw = (gridDim.x * blockDim.x) >> 6;
    for (int i = gw; i < N_NODES; i += nw) {
        uint e = offsets[i], e1 = offsets[i + 1];
        float2 acc = {0.f, 0.f};
        for (; e + 4 <= e1; e += 4) {
            int s0 = csr_src[e], s1 = csr_src[e + 1];
            int s2 = csr_src[e + 2], s3 = csr_src[e + 3];
            float2 v0 = __half22float2(Xr[(size_t)s0 * 64 + lane]);
            float2 v1 = __half22float2(Xr[(size_t)s1 * 64 + lane]);
            float2 v2 = __half22float2(Xr[(size_t)s2 * 64 + lane]);
            float2 v3 = __half22float2(Xr[(size_t)s3 * 64 + lane]);
            acc.x += (v0.x + v1.x) + (v2.x + v3.x);
            acc.y += (v0.y + v1.y) + (v2.y + v3.y);
        }
        for (; e < e1; ++e) {
            int s = csr_src[e];
            float2 v = __half22float2(Xr[(size_t)s * 64 + lane]);
            acc.x += v.x; acc.y += v.y;
        }
        float nd = rsqrtf(fmaxf((float)deg_in[i], 1.f));
        if (MODE == 1) {
            float ns = rsqrtf(fmaxf((float)deg_out[i], 1.f));
            float2 b = *(const float2*)&b1[lane * 2];
            float rx = fmaxf(acc.x * nd + b.x, 0.f) * ns;
            float ry = fmaxf(acc.y * nd + b.y, 0.f) * ns;
            ((__half2*)outp)[(size_t)i * 64 + lane] = __floats2half2_rn(rx, ry);
        } else {
            float2 r; r.x = acc.x * nd; r.y = acc.y * nd;
            ((float2*)outp)[(size_t)i * 64 + lane] = r;
        }
    }
}

// ---------------- parallel segmented pool: sums[g][t] += y rows ----------------
__global__ __launch_bounds__(128) void k_pool(const float* __restrict__ y,
                                              const int* __restrict__ gid,
                                              float* __restrict__ sums) {
    __shared__ int sg[PCH];
    const int b = blockIdx.x, t = threadIdx.x;
    const int base = b * PCH;
    if (t < PCH) sg[t] = gid[base + t];
    __syncthreads();
    float acc = 0.f;
    int cur = sg[0];
    for (int j = 0; j < PCH; ++j) {
        int g = sg[j];                       // uniform across block -> no divergence
        if (g != cur) {
            atomicAdd(&sums[cur * D + t], acc);
            acc = 0.f; cur = g;
        }
        acc += y[(size_t)(base + j) * D + t];
    }
    atomicAdd(&sums[cur * D + t], acc);
}

// ---------------- per-graph classifier matvec ----------------
__global__ __launch_bounds__(64) void k_out(const float* __restrict__ sums,
                                            const int* __restrict__ bounds,
                                            const float* __restrict__ Wfused,
                                            const float* __restrict__ bfused,
                                            const float* __restrict__ bc,
                                            float* __restrict__ out) {
    int g = blockIdx.x, c = threadIdx.x;
    if (c >= N_CLASSES) return;
    int cnt = bounds[g + 1] - bounds[g];
    float inv = (cnt > 0) ? 1.f / (float)cnt : 0.f;
    float s = 0.f;
    #pragma unroll 8
    for (int k = 0; k < D; ++k) s += sums[g * D + k] * Wfused[k * N_CLASSES + c];
    out[g * N_CLASSES + c] = s * inv + (cnt > 0 ? bfused[c] : 0.f) + bc[c];
}

extern "C" void kernel_launch(void* const* d_in, const int* in_sizes, int n_in,
                              void* d_out, int out_size, void* d_ws, size_t ws_size,
                              hipStream_t stream) {
    const float* feat = (const float*)d_in[0];
    const float* W1   = (const float*)d_in[1];
    const float* b1   = (const float*)d_in[2];
    const float* W2   = (const float*)d_in[3];
    const float* b2   = (const float*)d_in[4];
    const float* Wc   = (const float*)d_in[5];
    const float* bc   = (const float*)d_in[6];
    const int*   src  = (const int*)d_in[7];
    const int*   dst  = (const int*)d_in[8];
    const int*   gid  = (const int*)d_in[9];
    float* out = (float*)d_out;

    char* w = (char*)d_ws;
    uint* deg_out = (uint*)w; w += (size_t)N_NODES * 4;
    uint* deg_in  = (uint*)w; w += (size_t)N_NODES * 4;
    uint* offsets = (uint*)w; w += (size_t)(N_NODES + 4) * 4;
    uint* cursor  = (uint*)w; w += (size_t)N_NODES * 4;
    int*  csr     = (int*)w;  w += (size_t)N_EDGES * 4;
    int*  bounds  = (int*)w;  w += 132 * 4;
    uint* blksum  = (uint*)w; w += 32 * 4;
    uint* blkbase = (uint*)w; w += 32 * 4;
    float* Wfused = (float*)w; w += (size_t)D * N_CLASSES * 4;
    float* bfused = (float*)w; w += 64 * 4;
    float* sums   = (float*)w; w += (size_t)N_GRAPHS * D * 4;
    __half* hW  = (__half*)w; w += (size_t)N_NODES * D * 2;
    __half* h1s = (__half*)w; w += (size_t)N_NODES * D * 2;
    float* y    = (float*)w;  w += (size_t)N_NODES * D * 4;

    hipMemsetAsync(deg_out, 0, (size_t)N_NODES * 4, stream);
    hipMemsetAsync(deg_in, 0, (size_t)N_NODES * 4, stream);
    hipMemsetAsync(sums, 0, (size_t)N_GRAPHS * D * 4, stream);

    k_fuse<<<D + 1, 64, 0, stream>>>(W2, b2, Wc, Wfused, bfused);
    k_deg<<<1024, 256, 0, stream>>>(src, dst, deg_out, deg_in);
    k_scan_a<<<SCAN_NB, 256, 0, stream>>>(deg_in, blksum);
    k_scan_b<<<1, 64, 0, stream>>>(blksum, blkbase);
    k_scan_c<<<SCAN_NB, 256, 0, stream>>>(deg_in, blkbase, offsets, cursor, gid, bounds);
    k_fill<<<1024, 256, 0, stream>>>(src, dst, cursor, csr);
    k_gemm1<<<640, 256, 0, stream>>>(feat, W1, deg_out, hW);
    k_spmm<1><<<2048, 256, 0, stream>>>(hW, csr, offsets, deg_out, deg_in, b1, h1s);
    k_spmm<2><<<2048, 256, 0, stream>>>(h1s, csr, offsets, deg_out, deg_in, b1, y);
    k_pool<<<POOL_NB, 128, 0, stream>>>(y, gid, sums);
    k_out<<<N_GRAPHS, 64, 0, stream>>>(sums, bounds, Wfused, bfused, bc, out);
}

// Round 7
// 220.066 us; speedup vs baseline: 1.9189x; 1.1387x over previous
//
#include <hip/hip_runtime.h>
#include <hip/hip_fp16.h>

#define N_NODES   40000
#define N_EDGES   640000
#define D         128
#define N_CLASSES 40
#define N_GRAPHS  128

#define SCAN_CHUNK 2048
#define SCAN_NB    ((N_NODES + SCAN_CHUNK - 1) / SCAN_CHUNK)   // 20
#define PCH 64
#define POOL_NB (N_NODES / PCH)                                 // 625

#define NB_H    40
#define CHUNK_H (N_EDGES / NB_H)        // 16000 (< 65536 so u16 counts can't overflow)
#define NWORDS  (N_NODES / 2)           // 20000 u32 words of packed u16 counters

typedef unsigned int uint;

// ---------------- per-block LDS histogram (u16-packed, no global atomics) ------
__global__ __launch_bounds__(1024) void k_hist(const int* __restrict__ idx,
                                               uint* __restrict__ cnt) {
    __shared__ uint h[NWORDS];          // 80 KB
    const int b = blockIdx.x, t = threadIdx.x;
    for (int i = t; i < NWORDS; i += 1024) h[i] = 0;
    __syncthreads();
    const int base = b * CHUNK_H;
    for (int e = t; e < CHUNK_H; e += 1024) {
        int v = idx[base + e];
        atomicAdd(&h[v >> 1], 1u << ((v & 1) * 16));
    }
    __syncthreads();
    for (int i = t; i < NWORDS; i += 1024) cnt[(size_t)b * NWORDS + i] = h[i];
}

// ---------------- deg[i] = sum over blocks of per-block counts ----------------
__global__ void k_degsum(const uint* __restrict__ cntS, const uint* __restrict__ cntD,
                         uint* __restrict__ deg_out, uint* __restrict__ deg_in) {
    int w = blockIdx.x * blockDim.x + threadIdx.x;
    if (w >= NWORDS) return;
    uint s0 = 0, s1 = 0, d0 = 0, d1 = 0;
    for (int b = 0; b < NB_H; ++b) {
        uint cs = cntS[(size_t)b * NWORDS + w];
        uint cd = cntD[(size_t)b * NWORDS + w];
        s0 += cs & 0xffffu; s1 += cs >> 16;
        d0 += cd & 0xffffu; d1 += cd >> 16;
    }
    deg_out[2 * w] = s0; deg_out[2 * w + 1] = s1;
    deg_in[2 * w]  = d0; deg_in[2 * w + 1]  = d1;
}

// ---------------- two-level scan: A = per-block sum ----------------
__global__ __launch_bounds__(256) void k_scan_a(const uint* __restrict__ deg_in,
                                                uint* __restrict__ blksum) {
    __shared__ uint wsum[4];
    const int b = blockIdx.x, t = threadIdx.x;
    const int lane = t & 63, wave = t >> 6;
    int base = b * SCAN_CHUNK + t * 8;
    uint s = 0;
    #pragma unroll
    for (int j = 0; j < 8; ++j) {
        int idx = base + j;
        s += (idx < N_NODES) ? deg_in[idx] : 0u;
    }
    #pragma unroll
    for (int off = 32; off > 0; off >>= 1) s += __shfl_down(s, off);
    if (lane == 0) wsum[wave] = s;
    __syncthreads();
    if (t == 0) blksum[b] = wsum[0] + wsum[1] + wsum[2] + wsum[3];
}

// ---------------- B = exclusive scan of block sums (1 wave) ----------------
__global__ void k_scan_b(const uint* __restrict__ blksum, uint* __restrict__ blkbase) {
    int t = threadIdx.x;   // 64 threads
    uint v = (t < SCAN_NB) ? blksum[t] : 0u;
    uint inc = v;
    #pragma unroll
    for (int off = 1; off < 64; off <<= 1) {
        uint o = __shfl_up(inc, off);
        if (t >= off) inc += o;
    }
    if (t < SCAN_NB) blkbase[t] = inc - v;
}

// ------ C = local scan + base, write offsets; also graph bounds ------
__global__ __launch_bounds__(256) void k_scan_c(const uint* __restrict__ deg_in,
                                                const uint* __restrict__ blkbase,
                                                uint* __restrict__ offsets,
                                                const int* __restrict__ gid,
                                                int* __restrict__ bounds) {
    __shared__ uint wsum[4];
    const int b = blockIdx.x, t = threadIdx.x;
    const int lane = t & 63, wave = t >> 6;
    int base = b * SCAN_CHUNK + t * 8;
    uint v[8];
    uint s = 0;
    #pragma unroll
    for (int j = 0; j < 8; ++j) {
        int idx = base + j;
        v[j] = (idx < N_NODES) ? deg_in[idx] : 0u;
        s += v[j];
    }
    uint inc = s;
    #pragma unroll
    for (int off = 1; off < 64; off <<= 1) {
        uint o = __shfl_up(inc, off);
        if (lane >= off) inc += o;
    }
    if (lane == 63) wsum[wave] = inc;
    __syncthreads();
    if (t < 4) {
        uint w = wsum[t];
        #pragma unroll
        for (int off = 1; off < 4; off <<= 1) {
            uint o = __shfl_up(w, off);
            if (t >= off) w += o;
        }
        wsum[t] = w;   // inclusive wave sums
    }
    __syncthreads();
    uint excl = inc - s + (wave ? wsum[wave - 1] : 0u) + blkbase[b];
    #pragma unroll
    for (int j = 0; j < 8; ++j) {
        int idx = base + j;
        if (idx < N_NODES) offsets[idx] = excl;
        excl += v[j];
    }
    if (b == SCAN_NB - 1 && t == 255) offsets[N_NODES] = excl;
    // ---- graph bounds (gid sorted) ----
    for (int j = 0; j < 8; ++j) {
        int idx = base + j;
        if (idx >= N_NODES) break;
        int g = gid[idx];
        if (idx == 0) {
            for (int q = 0; q <= g; ++q) bounds[q] = 0;
        } else {
            int gp = gid[idx - 1];
            for (int q = gp + 1; q <= g; ++q) bounds[q] = idx;
        }
        if (idx == N_NODES - 1) {
            for (int q = g + 1; q <= N_GRAPHS; ++q) bounds[q] = N_NODES;
        }
    }
}

// ------ per-(block,bin) CSR base = offsets[bin] + prefix of per-block counts ---
__global__ void k_base(const uint* __restrict__ cntD, const uint* __restrict__ offsets,
                       uint* __restrict__ baseD) {
    int i = blockIdx.x * blockDim.x + threadIdx.x;
    if (i >= N_NODES) return;
    uint run = offsets[i];
    for (int b = 0; b < NB_H; ++b) {
        baseD[(size_t)b * N_NODES + i] = run;
        run += (cntD[(size_t)b * NWORDS + (i >> 1)] >> ((i & 1) * 16)) & 0xffffu;
    }
}

// ------ CSR place via LDS rank cursors (no global atomics) ------
__global__ __launch_bounds__(1024) void k_place(const int* __restrict__ src,
                                                const int* __restrict__ dst,
                                                const uint* __restrict__ baseD,
                                                int* __restrict__ csr) {
    __shared__ uint rk[NWORDS];         // 80 KB, packed u16 ranks
    const int b = blockIdx.x, t = threadIdx.x;
    for (int i = t; i < NWORDS; i += 1024) rk[i] = 0;
    __syncthreads();
    const int base = b * CHUNK_H;
    for (int e = t; e < CHUNK_H; e += 1024) {
        int d = dst[base + e];
        uint sh = (d & 1) * 16;
        uint old = atomicAdd(&rk[d >> 1], 1u << sh);
        uint r = (old >> sh) & 0xffffu;
        csr[baseD[(size_t)b * N_NODES + d] + r] = src[base + e];
    }
}

// ---------------- fused classifier weight: Wfused = W2 @ Wc, bfused = b2 @ Wc ----
__global__ void k_fuse(const float* __restrict__ W2, const float* __restrict__ b2,
                       const float* __restrict__ Wc,
                       float* __restrict__ Wfused, float* __restrict__ bfused) {
    int k = blockIdx.x;        // 0..128 (128 = b2 row)
    int c = threadIdx.x;       // 64 threads, 40 active
    if (c >= N_CLASSES) return;
    const float* row = (k < D) ? &W2[k * D] : b2;
    float s = 0.f;
    for (int j = 0; j < D; ++j) s += row[j] * Wc[j * N_CLASSES + c];
    if (k < D) Wfused[k * N_CLASSES + c] = s;
    else bfused[c] = s;
}

// ---------------- GEMM1: hW = fp16( (feat @ W1) * norm_src )  ----------------
#define GR 16
__global__ __launch_bounds__(256) void k_gemm1(const float* __restrict__ feat,
                                               const float* __restrict__ W1,
                                               const uint* __restrict__ deg_out,
                                               __half* __restrict__ hW) {
    __shared__ float Ws[128 * 64];
    __shared__ float Fs[GR][132];
    const int t = threadIdx.x;
    const int rloc = t >> 4;
    const int j4 = t & 15;
    for (int half = 0; half < 2; ++half) {
        __syncthreads();
        for (int i = t; i < 128 * 16; i += 256) {
            int k = i >> 4, c4 = i & 15;
            *(float4*)&Ws[k * 64 + c4 * 4] =
                *(const float4*)&W1[k * 128 + half * 64 + c4 * 4];
        }
        __syncthreads();
        for (int rg = blockIdx.x; rg * GR < N_NODES; rg += gridDim.x) {
            int rowbase = rg * GR;
            __syncthreads();
            for (int i = t; i < GR * 32; i += 256) {
                int r = i >> 5, c4 = i & 31;
                *(float4*)&Fs[r][c4 * 4] =
                    *(const float4*)&feat[(rowbase + r) * 128 + c4 * 4];
            }
            __syncthreads();
            float4 acc = {0.f, 0.f, 0.f, 0.f};
            for (int k = 0; k < 128; ++k) {
                float f = Fs[rloc][k];
                float4 w = *(const float4*)&Ws[k * 64 + j4 * 4];
                acc.x += f * w.x; acc.y += f * w.y;
                acc.z += f * w.z; acc.w += f * w.w;
            }
            int row = rowbase + rloc;
            float ns = rsqrtf(fmaxf((float)deg_out[row], 1.f));
            __half2 p0 = __floats2half2_rn(acc.x * ns, acc.y * ns);
            __half2 p1 = __floats2half2_rn(acc.z * ns, acc.w * ns);
            uint2 pk;
            pk.x = *(uint*)&p0;
            pk.y = *(uint*)&p1;
            *(uint2*)&hW[(size_t)row * 128 + half * 64 + j4 * 4] = pk;
        }
    }
}

// ------- pull SpMM (fp16 gather, fp32 accum): one wave per node, lane = 2 feats ----
template <int MODE>
__global__ __launch_bounds__(256) void k_spmm(const __half* __restrict__ X,
                                              const int* __restrict__ csr_src,
                                              const uint* __restrict__ offsets,
                                              const uint* __restrict__ deg_out,
                                              const uint* __restrict__ deg_in,
                                              const float* __restrict__ b1,
                                              void* __restrict__ outp) {
    const int lane = threadIdx.x & 63;
    const __half2* __restrict__ Xr = (const __half2*)X;   // row = 64 half2
    int gw = (blockIdx.x * blockDim.x + threadIdx.x) >> 6;
    int nw = (gridDim.x * blockDim.x) >> 6;
    for (int i = gw; i < N_NODES; i += nw) {
        uint e = offsets[i], e1 = offsets[i + 1];
        float2 acc = {0.f, 0.f};
        for (; e + 4 <= e1; e += 4) {
            int s0 = csr_src[e], s1 = csr_src[e + 1];
            int s2 = csr_src[e + 2], s3 = csr_src[e + 3];
            float2 v0 = __half22float2(Xr[(size_t)s0 * 64 + lane]);
            float2 v1 = __half22float2(Xr[(size_t)s1 * 64 + lane]);
            float2 v2 = __half22float2(Xr[(size_t)s2 * 64 + lane]);
            float2 v3 = __half22float2(Xr[(size_t)s3 * 64 + lane]);
            acc.x += (v0.x + v1.x) + (v2.x + v3.x);
            acc.y += (v0.y + v1.y) + (v2.y + v3.y);
        }
        for (; e < e1; ++e) {
            int s = csr_src[e];
            float2 v = __half22float2(Xr[(size_t)s * 64 + lane]);
            acc.x += v.x; acc.y += v.y;
        }
        float nd = rsqrtf(fmaxf((float)deg_in[i], 1.f));
        if (MODE == 1) {
            float ns = rsqrtf(fmaxf((float)deg_out[i], 1.f));
            float2 b = *(const float2*)&b1[lane * 2];
            float rx = fmaxf(acc.x * nd + b.x, 0.f) * ns;
            float ry = fmaxf(acc.y * nd + b.y, 0.f) * ns;
            ((__half2*)outp)[(size_t)i * 64 + lane] = __floats2half2_rn(rx, ry);
        } else {
            float2 r; r.x = acc.x * nd; r.y = acc.y * nd;
            ((float2*)outp)[(size_t)i * 64 + lane] = r;
        }
    }
}

// ---------------- parallel segmented pool: sums[g][t] += y rows ----------------
__global__ __launch_bounds__(128) void k_pool(const float* __restrict__ y,
                                              const int* __restrict__ gid,
                                              float* __restrict__ sums) {
    __shared__ int sg[PCH];
    const int b = blockIdx.x, t = threadIdx.x;
    const int base = b * PCH;
    if (t < PCH) sg[t] = gid[base + t];
    __syncthreads();
    float acc = 0.f;
    int cur = sg[0];
    for (int j = 0; j < PCH; ++j) {
        int g = sg[j];                       // uniform across block -> no divergence
        if (g != cur) {
            atomicAdd(&sums[cur * D + t], acc);
            acc = 0.f; cur = g;
        }
        acc += y[(size_t)(base + j) * D + t];
    }
    atomicAdd(&sums[cur * D + t], acc);
}

// ---------------- per-graph classifier matvec ----------------
__global__ __launch_bounds__(64) void k_out(const float* __restrict__ sums,
                                            const int* __restrict__ bounds,
                                            const float* __restrict__ Wfused,
                                            const float* __restrict__ bfused,
                                            const float* __restrict__ bc,
                                            float* __restrict__ out) {
    int g = blockIdx.x, c = threadIdx.x;
    if (c >= N_CLASSES) return;
    int cnt = bounds[g + 1] - bounds[g];
    float inv = (cnt > 0) ? 1.f / (float)cnt : 0.f;
    float s = 0.f;
    #pragma unroll 8
    for (int k = 0; k < D; ++k) s += sums[g * D + k] * Wfused[k * N_CLASSES + c];
    out[g * N_CLASSES + c] = s * inv + (cnt > 0 ? bfused[c] : 0.f) + bc[c];
}

extern "C" void kernel_launch(void* const* d_in, const int* in_sizes, int n_in,
                              void* d_out, int out_size, void* d_ws, size_t ws_size,
                              hipStream_t stream) {
    const float* feat = (const float*)d_in[0];
    const float* W1   = (const float*)d_in[1];
    const float* b1   = (const float*)d_in[2];
    const float* W2   = (const float*)d_in[3];
    const float* b2   = (const float*)d_in[4];
    const float* Wc   = (const float*)d_in[5];
    const float* bc   = (const float*)d_in[6];
    const int*   src  = (const int*)d_in[7];
    const int*   dst  = (const int*)d_in[8];
    const int*   gid  = (const int*)d_in[9];
    float* out = (float*)d_out;

    char* w = (char*)d_ws;
    uint* deg_out = (uint*)w; w += (size_t)N_NODES * 4;
    uint* deg_in  = (uint*)w; w += (size_t)N_NODES * 4;
    uint* offsets = (uint*)w; w += (size_t)(N_NODES + 4) * 4;
    int*  csr     = (int*)w;  w += (size_t)N_EDGES * 4;
    int*  bounds  = (int*)w;  w += 132 * 4;
    uint* blksum  = (uint*)w; w += 32 * 4;
    uint* blkbase = (uint*)w; w += 32 * 4;
    float* Wfused = (float*)w; w += (size_t)D * N_CLASSES * 4;
    float* bfused = (float*)w; w += 64 * 4;
    float* sums   = (float*)w; w += (size_t)N_GRAPHS * D * 4;
    // cnt/base region (12.8MB) is dead after k_place; alias y (20.5MB) over it.
    char* region  = w;
    uint* cntS  = (uint*)region;                                     // 3.2 MB
    uint* cntD  = (uint*)(region + (size_t)NB_H * NWORDS * 4);       // 3.2 MB
    uint* baseD = (uint*)(region + (size_t)2 * NB_H * NWORDS * 4);   // 6.4 MB
    float* y    = (float*)region;                                    // 20.5 MB
    w = region + (size_t)N_NODES * D * 4;
    __half* hW  = (__half*)w; w += (size_t)N_NODES * D * 2;
    __half* h1s = (__half*)w; w += (size_t)N_NODES * D * 2;

    hipMemsetAsync(sums, 0, (size_t)N_GRAPHS * D * 4, stream);

    k_fuse<<<D + 1, 64, 0, stream>>>(W2, b2, Wc, Wfused, bfused);
    k_hist<<<NB_H, 1024, 0, stream>>>(src, cntS);
    k_hist<<<NB_H, 1024, 0, stream>>>(dst, cntD);
    k_degsum<<<(NWORDS + 255) / 256, 256, 0, stream>>>(cntS, cntD, deg_out, deg_in);
    k_scan_a<<<SCAN_NB, 256, 0, stream>>>(deg_in, blksum);
    k_scan_b<<<1, 64, 0, stream>>>(blksum, blkbase);
    k_scan_c<<<SCAN_NB, 256, 0, stream>>>(deg_in, blkbase, offsets, gid, bounds);
    k_base<<<(N_NODES + 255) / 256, 256, 0, stream>>>(cntD, offsets, baseD);
    k_place<<<NB_H, 1024, 0, stream>>>(src, dst, baseD, csr);
    k_gemm1<<<640, 256, 0, stream>>>(feat, W1, deg_out, hW);
    k_spmm<1><<<2048, 256, 0, stream>>>(hW, csr, offsets, deg_out, deg_in, b1, h1s);
    k_spmm<2><<<2048, 256, 0, stream>>>(h1s, csr, offsets, deg_out, deg_in, b1, y);
    k_pool<<<POOL_NB, 128, 0, stream>>>(y, gid, sums);
    k_out<<<N_GRAPHS, 64, 0, stream>>>(sums, bounds, Wfused, bfused, bc, out);
}

// Round 8
// 192.750 us; speedup vs baseline: 2.1908x; 1.1417x over previous
//
#include <hip/hip_runtime.h>
#include <hip/hip_fp16.h>

#define N_NODES   40000
#define N_EDGES   640000
#define D         128
#define N_CLASSES 40
#define N_GRAPHS  128

#define SCAN_CHUNK 2048
#define SCAN_NB    ((N_NODES + SCAN_CHUNK - 1) / SCAN_CHUNK)   // 20
#define PCH 64
#define POOL_NB (N_NODES / PCH)                                 // 625

#define NB_H    40
#define CHUNK_H (N_EDGES / NB_H)        // 16000 (< 65536 so u16 counts can't overflow)
#define NWORDS  (N_NODES / 2)           // 20000 u32 words of packed u16 counters

typedef unsigned int uint;
typedef _Float16 f16x8 __attribute__((ext_vector_type(8)));
typedef float f32x4 __attribute__((ext_vector_type(4)));

// ---------------- per-block LDS histogram (u16-packed, no global atomics) ------
__global__ __launch_bounds__(1024) void k_hist(const int* __restrict__ idx,
                                               uint* __restrict__ cnt) {
    __shared__ uint h[NWORDS];          // 80 KB
    const int b = blockIdx.x, t = threadIdx.x;
    for (int i = t; i < NWORDS; i += 1024) h[i] = 0;
    __syncthreads();
    const int base = b * CHUNK_H;
    for (int e = t; e < CHUNK_H; e += 1024) {
        int v = idx[base + e];
        atomicAdd(&h[v >> 1], 1u << ((v & 1) * 16));
    }
    __syncthreads();
    for (int i = t; i < NWORDS; i += 1024) cnt[(size_t)b * NWORDS + i] = h[i];
}

// ---------------- deg[i] = sum over blocks of per-block counts ----------------
__global__ void k_degsum(const uint* __restrict__ cntS, const uint* __restrict__ cntD,
                         uint* __restrict__ deg_out, uint* __restrict__ deg_in) {
    int w = blockIdx.x * blockDim.x + threadIdx.x;
    if (w >= NWORDS) return;
    uint s0 = 0, s1 = 0, d0 = 0, d1 = 0;
    for (int b = 0; b < NB_H; ++b) {
        uint cs = cntS[(size_t)b * NWORDS + w];
        uint cd = cntD[(size_t)b * NWORDS + w];
        s0 += cs & 0xffffu; s1 += cs >> 16;
        d0 += cd & 0xffffu; d1 += cd >> 16;
    }
    deg_out[2 * w] = s0; deg_out[2 * w + 1] = s1;
    deg_in[2 * w]  = d0; deg_in[2 * w + 1]  = d1;
}

// ---------------- two-level scan: A = per-block sum ----------------
__global__ __launch_bounds__(256) void k_scan_a(const uint* __restrict__ deg_in,
                                                uint* __restrict__ blksum) {
    __shared__ uint wsum[4];
    const int b = blockIdx.x, t = threadIdx.x;
    const int lane = t & 63, wave = t >> 6;
    int base = b * SCAN_CHUNK + t * 8;
    uint s = 0;
    #pragma unroll
    for (int j = 0; j < 8; ++j) {
        int idx = base + j;
        s += (idx < N_NODES) ? deg_in[idx] : 0u;
    }
    #pragma unroll
    for (int off = 32; off > 0; off >>= 1) s += __shfl_down(s, off);
    if (lane == 0) wsum[wave] = s;
    __syncthreads();
    if (t == 0) blksum[b] = wsum[0] + wsum[1] + wsum[2] + wsum[3];
}

// ---------------- B = exclusive scan of block sums (1 wave) ----------------
__global__ void k_scan_b(const uint* __restrict__ blksum, uint* __restrict__ blkbase) {
    int t = threadIdx.x;   // 64 threads
    uint v = (t < SCAN_NB) ? blksum[t] : 0u;
    uint inc = v;
    #pragma unroll
    for (int off = 1; off < 64; off <<= 1) {
        uint o = __shfl_up(inc, off);
        if (t >= off) inc += o;
    }
    if (t < SCAN_NB) blkbase[t] = inc - v;
}

// ------ C = local scan + base, write offsets; also graph bounds ------
__global__ __launch_bounds__(256) void k_scan_c(const uint* __restrict__ deg_in,
                                                const uint* __restrict__ blkbase,
                                                uint* __restrict__ offsets,
                                                const int* __restrict__ gid,
                                                int* __restrict__ bounds) {
    __shared__ uint wsum[4];
    const int b = blockIdx.x, t = threadIdx.x;
    const int lane = t & 63, wave = t >> 6;
    int base = b * SCAN_CHUNK + t * 8;
    uint v[8];
    uint s = 0;
    #pragma unroll
    for (int j = 0; j < 8; ++j) {
        int idx = base + j;
        v[j] = (idx < N_NODES) ? deg_in[idx] : 0u;
        s += v[j];
    }
    uint inc = s;
    #pragma unroll
    for (int off = 1; off < 64; off <<= 1) {
        uint o = __shfl_up(inc, off);
        if (lane >= off) inc += o;
    }
    if (lane == 63) wsum[wave] = inc;
    __syncthreads();
    if (t < 4) {
        uint w = wsum[t];
        #pragma unroll
        for (int off = 1; off < 4; off <<= 1) {
            uint o = __shfl_up(w, off);
            if (t >= off) w += o;
        }
        wsum[t] = w;   // inclusive wave sums
    }
    __syncthreads();
    uint excl = inc - s + (wave ? wsum[wave - 1] : 0u) + blkbase[b];
    #pragma unroll
    for (int j = 0; j < 8; ++j) {
        int idx = base + j;
        if (idx < N_NODES) offsets[idx] = excl;
        excl += v[j];
    }
    if (b == SCAN_NB - 1 && t == 255) offsets[N_NODES] = excl;
    // ---- graph bounds (gid sorted) ----
    for (int j = 0; j < 8; ++j) {
        int idx = base + j;
        if (idx >= N_NODES) break;
        int g = gid[idx];
        if (idx == 0) {
            for (int q = 0; q <= g; ++q) bounds[q] = 0;
        } else {
            int gp = gid[idx - 1];
            for (int q = gp + 1; q <= g; ++q) bounds[q] = idx;
        }
        if (idx == N_NODES - 1) {
            for (int q = g + 1; q <= N_GRAPHS; ++q) bounds[q] = N_NODES;
        }
    }
}

// ------ per-(block,bin) CSR base = offsets[bin] + prefix of per-block counts ---
__global__ void k_base(const uint* __restrict__ cntD, const uint* __restrict__ offsets,
                       uint* __restrict__ baseD) {
    int i = blockIdx.x * blockDim.x + threadIdx.x;
    if (i >= N_NODES) return;
    uint run = offsets[i];
    for (int b = 0; b < NB_H; ++b) {
        baseD[(size_t)b * N_NODES + i] = run;
        run += (cntD[(size_t)b * NWORDS + (i >> 1)] >> ((i & 1) * 16)) & 0xffffu;
    }
}

// ------ CSR place via LDS rank cursors (no global atomics) ------
__global__ __launch_bounds__(1024) void k_place(const int* __restrict__ src,
                                                const int* __restrict__ dst,
                                                const uint* __restrict__ baseD,
                                                int* __restrict__ csr) {
    __shared__ uint rk[NWORDS];         // 80 KB, packed u16 ranks
    const int b = blockIdx.x, t = threadIdx.x;
    for (int i = t; i < NWORDS; i += 1024) rk[i] = 0;
    __syncthreads();
    const int base = b * CHUNK_H;
    for (int e = t; e < CHUNK_H; e += 1024) {
        int d = dst[base + e];
        uint sh = (d & 1) * 16;
        uint old = atomicAdd(&rk[d >> 1], 1u << sh);
        uint r = (old >> sh) & 0xffffu;
        csr[baseD[(size_t)b * N_NODES + d] + r] = src[base + e];
    }
}

// ---------------- fused classifier weight: Wfused = W2 @ Wc, bfused = b2 @ Wc ----
__global__ void k_fuse(const float* __restrict__ W2, const float* __restrict__ b2,
                       const float* __restrict__ Wc,
                       float* __restrict__ Wfused, float* __restrict__ bfused) {
    int k = blockIdx.x;        // 0..128 (128 = b2 row)
    int c = threadIdx.x;       // 64 threads, 40 active
    if (c >= N_CLASSES) return;
    const float* row = (k < D) ? &W2[k * D] : b2;
    float s = 0.f;
    for (int j = 0; j < D; ++j) s += row[j] * Wc[j * N_CLASSES + c];
    if (k < D) Wfused[k * N_CLASSES + c] = s;
    else bfused[c] = s;
}

// -------- GEMM1 via MFMA: hW = fp16( (feat @ W1) * norm_src ) ----------------
// 625 blocks x 4 waves; wave owns 16 rows x 128 cols. W1 (fp16 frags) fully
// VGPR-resident (32 frags); A loaded from global fp32 (full line utilization).
// Layouts (16x16x32): A: lane holds row=l&15, k=(l>>4)*8+i. B: k=(l>>4)*8+i,
// col=l&15. D: col=l&15, row=(l>>4)*4+reg (guide-verified).
__global__ __launch_bounds__(256, 1) void k_gemm1(const float* __restrict__ feat,
                                                  const float* __restrict__ W1,
                                                  const uint* __restrict__ deg_out,
                                                  __half* __restrict__ hW) {
    const int t = threadIdx.x;
    const int wv = t >> 6, l = t & 63;
    const int kg = l >> 4;          // k-group 0..3
    const int c  = l & 15;          // col-in-tile / row-in-tile
    const int r0 = blockIdx.x * 64 + wv * 16;

    // ---- B fragments: 4 K-steps x 8 N-tiles ----
    f16x8 B[4][8];
    #pragma unroll
    for (int ks = 0; ks < 4; ++ks) {
        #pragma unroll
        for (int nt = 0; nt < 8; ++nt) {
            const int kb = ks * 32 + kg * 8;
            const int col = nt * 16 + c;
            f16x8 b;
            #pragma unroll
            for (int i = 0; i < 8; ++i)
                b[i] = (_Float16)W1[(kb + i) * D + col];
            B[ks][nt] = b;
        }
    }

    // ---- accumulate ----
    f32x4 acc[8];
    #pragma unroll
    for (int nt = 0; nt < 8; ++nt) acc[nt] = (f32x4){0.f, 0.f, 0.f, 0.f};

    const int arow = r0 + c;
    #pragma unroll
    for (int ks = 0; ks < 4; ++ks) {
        const float4 q0 = *(const float4*)&feat[(size_t)arow * D + ks * 32 + kg * 8];
        const float4 q1 = *(const float4*)&feat[(size_t)arow * D + ks * 32 + kg * 8 + 4];
        f16x8 a;
        a[0] = (_Float16)q0.x; a[1] = (_Float16)q0.y;
        a[2] = (_Float16)q0.z; a[3] = (_Float16)q0.w;
        a[4] = (_Float16)q1.x; a[5] = (_Float16)q1.y;
        a[6] = (_Float16)q1.z; a[7] = (_Float16)q1.w;
        #pragma unroll
        for (int nt = 0; nt < 8; ++nt)
            acc[nt] = __builtin_amdgcn_mfma_f32_16x16x32_f16(a, B[ks][nt], acc[nt], 0, 0, 0);
    }

    // ---- epilogue: * norm_src, cast fp16, store ----
    const int rloc = kg * 4;
    float ns[4];
    #pragma unroll
    for (int r = 0; r < 4; ++r)
        ns[r] = rsqrtf(fmaxf((float)deg_out[r0 + rloc + r], 1.f));
    #pragma unroll
    for (int nt = 0; nt < 8; ++nt) {
        #pragma unroll
        for (int r = 0; r < 4; ++r)
            hW[(size_t)(r0 + rloc + r) * D + nt * 16 + c] =
                __float2half(acc[nt][r] * ns[r]);
    }
}

// ------- pull SpMM (fp16 gather, fp32 accum): one wave per node, lane = 2 feats ----
template <int MODE>
__global__ __launch_bounds__(256) void k_spmm(const __half* __restrict__ X,
                                              const int* __restrict__ csr_src,
                                              const uint* __restrict__ offsets,
                                              const uint* __restrict__ deg_out,
                                              const uint* __restrict__ deg_in,
                                              const float* __restrict__ b1,
                                              void* __restrict__ outp) {
    const int lane = threadIdx.x & 63;
    const __half2* __restrict__ Xr = (const __half2*)X;   // row = 64 half2
    int gw = (blockIdx.x * blockDim.x + threadIdx.x) >> 6;
    int nw = (gridDim.x * blockDim.x) >> 6;
    for (int i = gw; i < N_NODES; i += nw) {
        uint e = offsets[i], e1 = offsets[i + 1];
        float2 acc = {0.f, 0.f};
        for (; e + 4 <= e1; e += 4) {
            int s0 = csr_src[e], s1 = csr_src[e + 1];
            int s2 = csr_src[e + 2], s3 = csr_src[e + 3];
            float2 v0 = __half22float2(Xr[(size_t)s0 * 64 + lane]);
            float2 v1 = __half22float2(Xr[(size_t)s1 * 64 + lane]);
            float2 v2 = __half22float2(Xr[(size_t)s2 * 64 + lane]);
            float2 v3 = __half22float2(Xr[(size_t)s3 * 64 + lane]);
            acc.x += (v0.x + v1.x) + (v2.x + v3.x);
            acc.y += (v0.y + v1.y) + (v2.y + v3.y);
        }
        for (; e < e1; ++e) {
            int s = csr_src[e];
            float2 v = __half22float2(Xr[(size_t)s * 64 + lane]);
            acc.x += v.x; acc.y += v.y;
        }
        float nd = rsqrtf(fmaxf((float)deg_in[i], 1.f));
        if (MODE == 1) {
            float ns = rsqrtf(fmaxf((float)deg_out[i], 1.f));
            float2 b = *(const float2*)&b1[lane * 2];
            float rx = fmaxf(acc.x * nd + b.x, 0.f) * ns;
            float ry = fmaxf(acc.y * nd + b.y, 0.f) * ns;
            ((__half2*)outp)[(size_t)i * 64 + lane] = __floats2half2_rn(rx, ry);
        } else {
            float2 r; r.x = acc.x * nd; r.y = acc.y * nd;
            ((float2*)outp)[(size_t)i * 64 + lane] = r;
        }
    }
}

// ---------------- parallel segmented pool: sums[g][t] += y rows ----------------
__global__ __launch_bounds__(128) void k_pool(const float* __restrict__ y,
                                              const int* __restrict__ gid,
                                              float* __restrict__ sums) {
    __shared__ int sg[PCH];
    const int b = blockIdx.x, t = threadIdx.x;
    const int base = b * PCH;
    if (t < PCH) sg[t] = gid[base + t];
    __syncthreads();
    float acc = 0.f;
    int cur = sg[0];
    for (int j = 0; j < PCH; ++j) {
        int g = sg[j];                       // uniform across block -> no divergence
        if (g != cur) {
            atomicAdd(&sums[cur * D + t], acc);
            acc = 0.f; cur = g;
        }
        acc += y[(size_t)(base + j) * D + t];
    }
    atomicAdd(&sums[cur * D + t], acc);
}

// ---------------- per-graph classifier matvec ----------------
__global__ __launch_bounds__(64) void k_out(const float* __restrict__ sums,
                                            const int* __restrict__ bounds,
                                            const float* __restrict__ Wfused,
                                            const float* __restrict__ bfused,
                                            const float* __restrict__ bc,
                                            float* __restrict__ out) {
    int g = blockIdx.x, c = threadIdx.x;
    if (c >= N_CLASSES) return;
    int cnt = bounds[g + 1] - bounds[g];
    float inv = (cnt > 0) ? 1.f / (float)cnt : 0.f;
    float s = 0.f;
    #pragma unroll 8
    for (int k = 0; k < D; ++k) s += sums[g * D + k] * Wfused[k * N_CLASSES + c];
    out[g * N_CLASSES + c] = s * inv + (cnt > 0 ? bfused[c] : 0.f) + bc[c];
}

extern "C" void kernel_launch(void* const* d_in, const int* in_sizes, int n_in,
                              void* d_out, int out_size, void* d_ws, size_t ws_size,
                              hipStream_t stream) {
    const float* feat = (const float*)d_in[0];
    const float* W1   = (const float*)d_in[1];
    const float* b1   = (const float*)d_in[2];
    const float* W2   = (const float*)d_in[3];
    const float* b2   = (const float*)d_in[4];
    const float* Wc   = (const float*)d_in[5];
    const float* bc   = (const float*)d_in[6];
    const int*   src  = (const int*)d_in[7];
    const int*   dst  = (const int*)d_in[8];
    const int*   gid  = (const int*)d_in[9];
    float* out = (float*)d_out;

    char* w = (char*)d_ws;
    uint* deg_out = (uint*)w; w += (size_t)N_NODES * 4;
    uint* deg_in  = (uint*)w; w += (size_t)N_NODES * 4;
    uint* offsets = (uint*)w; w += (size_t)(N_NODES + 4) * 4;
    int*  csr     = (int*)w;  w += (size_t)N_EDGES * 4;
    int*  bounds  = (int*)w;  w += 132 * 4;
    uint* blksum  = (uint*)w; w += 32 * 4;
    uint* blkbase = (uint*)w; w += 32 * 4;
    float* Wfused = (float*)w; w += (size_t)D * N_CLASSES * 4;
    float* bfused = (float*)w; w += 64 * 4;
    float* sums   = (float*)w; w += (size_t)N_GRAPHS * D * 4;
    // cnt/base region (12.8MB) is dead after k_place; alias y (20.5MB) over it.
    char* region  = w;
    uint* cntS  = (uint*)region;                                     // 3.2 MB
    uint* cntD  = (uint*)(region + (size_t)NB_H * NWORDS * 4);       // 3.2 MB
    uint* baseD = (uint*)(region + (size_t)2 * NB_H * NWORDS * 4);   // 6.4 MB
    float* y    = (float*)region;                                    // 20.5 MB
    w = region + (size_t)N_NODES * D * 4;
    __half* hW  = (__half*)w; w += (size_t)N_NODES * D * 2;
    __half* h1s = (__half*)w; w += (size_t)N_NODES * D * 2;

    hipMemsetAsync(sums, 0, (size_t)N_GRAPHS * D * 4, stream);

    k_fuse<<<D + 1, 64, 0, stream>>>(W2, b2, Wc, Wfused, bfused);
    k_hist<<<NB_H, 1024, 0, stream>>>(src, cntS);
    k_hist<<<NB_H, 1024, 0, stream>>>(dst, cntD);
    k_degsum<<<(NWORDS + 255) / 256, 256, 0, stream>>>(cntS, cntD, deg_out, deg_in);
    k_scan_a<<<SCAN_NB, 256, 0, stream>>>(deg_in, blksum);
    k_scan_b<<<1, 64, 0, stream>>>(blksum, blkbase);
    k_scan_c<<<SCAN_NB, 256, 0, stream>>>(deg_in, blkbase, offsets, gid, bounds);
    k_base<<<(N_NODES + 255) / 256, 256, 0, stream>>>(cntD, offsets, baseD);
    k_place<<<NB_H, 1024, 0, stream>>>(src, dst, baseD, csr);
    k_gemm1<<<625, 256, 0, stream>>>(feat, W1, deg_out, hW);
    k_spmm<1><<<2048, 256, 0, stream>>>(hW, csr, offsets, deg_out, deg_in, b1, h1s);
    k_spmm<2><<<2048, 256, 0, stream>>>(h1s, csr, offsets, deg_out, deg_in, b1, y);
    k_pool<<<POOL_NB, 128, 0, stream>>>(y, gid, sums);
    k_out<<<N_GRAPHS, 64, 0, stream>>>(sums, bounds, Wfused, bfused, bc, out);
}